// Round 5
// baseline (952.786 us; speedup 1.0000x reference)
//
#include <hip/hip_runtime.h>

#define BB 4
#define CG 8
#define HH 240
#define WW 1216
#define HW (HH*WW)
#define NPIX (BB*HW)

struct __attribute__((packed, aligned(4))) Tap {
    unsigned pack;   // y0+1 (9b) | (x0+1)<<9... see encode below
    unsigned frac;   // ty q16 | tx q16 << 16
    float    av;     // exact affinity
};

// ---------------- fused conv + offsets/affinities + tap precompute ----------------
__global__ __launch_bounds__(256, 4) void conv_fused(
    const float* __restrict__ g, const float* __restrict__ cw,
    const float* __restrict__ cb, const float* __restrict__ asc,
    const float* __restrict__ feat_init, const float* __restrict__ conf,
    float* __restrict__ out_off, float* __restrict__ out_aff,
    float* __restrict__ out_scale,
    Tap* __restrict__ tp, float* __restrict__ fc0)
{
    int gid = blockIdx.x * 256 + threadIdx.x;
    if (gid == 0) out_scale[0] = asc[0];
    if (gid >= NPIX) return;
    int w = gid % WW;
    int tmp = gid / WW;
    int h = tmp % HH;
    int b = tmp / HH;

    float acc[24];
    #pragma unroll
    for (int o = 0; o < 24; ++o) acc[o] = cb[o];

    const float* gb = g + (size_t)b * CG * HW;
    for (int i = 0; i < CG; ++i) {
        #pragma unroll
        for (int kh = 0; kh < 3; ++kh) {
            int y = h + kh - 1;
            if ((unsigned)y >= (unsigned)HH) continue;
            #pragma unroll
            for (int kw = 0; kw < 3; ++kw) {
                int x = w + kw - 1;
                if ((unsigned)x >= (unsigned)WW) continue;
                float xv = gb[i * HW + y * WW + x];
                #pragma unroll
                for (int o = 0; o < 24; ++o)
                    acc[o] = fmaf(xv, cw[((o * CG + i) * 3 + kh) * 3 + kw], acc[o]);
            }
        }
    }

    int pix = h * WW + w;

    // offsets per neighbor k (zero pair inserted at k=4)
    float oyk[9], oxk[9];
    #pragma unroll
    for (int k = 0; k < 9; ++k) {
        if (k < 4)       { oyk[k] = acc[2 * k];     oxk[k] = acc[2 * k + 1]; }
        else if (k == 4) { oyk[k] = 0.0f;           oxk[k] = 0.0f; }
        else             { oyk[k] = acc[2 * k - 2]; oxk[k] = acc[2 * k - 1]; }
        __builtin_nontemporal_store(oyk[k], &out_off[(size_t)(b * 18 + 2 * k) * HW + pix]);
        __builtin_nontemporal_store(oxk[k], &out_off[(size_t)(b * 18 + 2 * k + 1) * HW + pix]);
    }

    // affinities
    float inv = 1.0f / (asc[0] + 1e-8f);
    float a[8];
    float s = 0.0f;
    #pragma unroll
    for (int c = 0; c < 8; ++c) {
        a[c] = tanhf(acc[16 + c]) * inv;
        s += fabsf(a[c]);
    }
    s += 1e-4f;
    s = fmaxf(s, 1.0f);
    float sum = 0.0f;
    #pragma unroll
    for (int c = 0; c < 8; ++c) {
        a[c] = a[c] / s;
        sum += a[c];
    }
    float a9[9];
    #pragma unroll
    for (int c = 0; c < 4; ++c) a9[c] = a[c];
    a9[4] = 1.0f - sum;
    #pragma unroll
    for (int c = 4; c < 8; ++c) a9[c + 1] = a[c];

    #pragma unroll
    for (int k = 0; k < 9; ++k)
        __builtin_nontemporal_store(a9[k], &out_aff[(size_t)(b * 9 + k) * HW + pix]);

    if (tp) {
        #pragma unroll
        for (int k = 0; k < 9; ++k) {
            float yy = (float)(h + k / 3 - 1) + oyk[k];
            float xx = (float)(w + k % 3 - 1) + oxk[k];
            float y0f = floorf(yy), x0f = floorf(xx);
            float ty = yy - y0f, tx = xx - x0f;

            unsigned vy0 = (y0f >= 0.0f   && y0f <= 239.0f)  ? 1u : 0u;
            unsigned vy1 = (y0f >= -1.0f  && y0f <= 238.0f)  ? 1u : 0u;
            unsigned vx0 = (x0f >= 0.0f   && x0f <= 1215.0f) ? 1u : 0u;
            unsigned vx1 = (x0f >= -1.0f  && x0f <= 1214.0f) ? 1u : 0u;

            int y0i = (int)fminf(fmaxf(y0f, -1.0f), 239.0f);
            int x0i = (int)fminf(fmaxf(x0f, -1.0f), 1215.0f);

            unsigned pack = (unsigned)(y0i + 1) | ((unsigned)(x0i + 1) << 8)
                          | (vy0 << 19) | (vy1 << 20) | (vx0 << 21) | (vx1 << 22);
            unsigned tyq = (unsigned)(fminf(ty, 0.99999f) * 65535.0f + 0.5f);
            unsigned txq = (unsigned)(fminf(tx, 0.99999f) * 65535.0f + 0.5f);

            Tap* t = &tp[(size_t)k * NPIX + gid];
            __builtin_nontemporal_store(pack, &t->pack);
            __builtin_nontemporal_store(tyq | (txq << 16), &t->frac);
            __builtin_nontemporal_store(a9[k], &t->av);
        }
        fc0[gid] = feat_init[gid] * conf[gid];
    }
}

// ---------------- propagation with compressed taps ----------------
__global__ __launch_bounds__(256, 4) void prop2(
    const float* __restrict__ fcIn, const float* __restrict__ conf,
    const Tap* __restrict__ tp,
    float* __restrict__ fout, float* __restrict__ fcOut, float* __restrict__ ffinal)
{
    int gid = blockIdx.x * 256 + threadIdx.x;
    if (gid >= NPIX) return;
    int b = gid / HW;
    const float* fcb = fcIn + (size_t)b * HW;

    float res = 0.0f;
    #pragma unroll
    for (int k = 0; k < 9; ++k) {
        const Tap* t = &tp[(size_t)k * NPIX + gid];
        unsigned Px = __builtin_nontemporal_load(&t->pack);
        unsigned Py = __builtin_nontemporal_load(&t->frac);
        float    av = __builtin_nontemporal_load(&t->av);

        int y0 = (int)(Px & 0xffu) - 1;
        int x0 = (int)((Px >> 8) & 0x7ffu) - 1;
        float ty = (float)(Py & 0xffffu) * (1.0f / 65535.0f);
        float tx = (float)(Py >> 16)     * (1.0f / 65535.0f);
        float fy0 = (Px & (1u << 19)) ? 1.0f : 0.0f;
        float fy1 = (Px & (1u << 20)) ? 1.0f : 0.0f;
        float fx0 = (Px & (1u << 21)) ? 1.0f : 0.0f;
        float fx1 = (Px & (1u << 22)) ? 1.0f : 0.0f;

        float cy0 = fy0 * (1.0f - ty), cy1 = fy1 * ty;
        float cx0 = fx0 * (1.0f - tx), cx1 = fx1 * tx;

        int yA = max(y0, 0), yB = min(y0 + 1, HH - 1);
        int xA = max(x0, 0), xB = min(x0 + 1, WW - 1);
        int rA = yA * WW, rB = yB * WW;

        float u0 = fmaf(cx1, fcb[rA + xB], cx0 * fcb[rA + xA]);
        float u1 = fmaf(cx1, fcb[rB + xB], cx0 * fcb[rB + xA]);
        res = fmaf(av, fmaf(cy1, u1, cy0 * u0), res);
    }
    __builtin_nontemporal_store(res, &fout[gid]);
    if (fcOut)  __builtin_nontemporal_store(res * conf[gid], &fcOut[gid]);
    if (ffinal) __builtin_nontemporal_store(res, &ffinal[gid]);
}

// ---------------- fallback prop (no workspace needed) ----------------
__device__ __forceinline__ float sampPC(const float* __restrict__ fb,
                                        const float* __restrict__ cf,
                                        int y, int x) {
    bool valid = ((unsigned)y < (unsigned)HH) && ((unsigned)x < (unsigned)WW);
    int yc = min(max(y, 0), HH - 1);
    int xc = min(max(x, 0), WW - 1);
    int idx = yc * WW + xc;
    float v = fb[idx] * cf[idx];
    return valid ? v : 0.0f;
}

__global__ __launch_bounds__(256, 4) void prop(
    const float* __restrict__ fp, const float* __restrict__ conf,
    const float* __restrict__ off, const float* __restrict__ aff,
    float* __restrict__ fout, float* __restrict__ ffinal)
{
    int gid = blockIdx.x * 256 + threadIdx.x;
    if (gid >= NPIX) return;
    int w = gid % WW;
    int tmp = gid / WW;
    int h = tmp % HH;
    int b = tmp / HH;
    int pix = h * WW + w;

    const float* fb = fp + (size_t)b * HW;
    const float* cf = conf + (size_t)b * HW;

    float res = 0.0f;
    #pragma unroll
    for (int k = 0; k < 9; ++k) {
        float oy = off[(size_t)(b * 18 + 2 * k) * HW + pix];
        float ox = off[(size_t)(b * 18 + 2 * k + 1) * HW + pix];
        float av = aff[(size_t)(b * 9 + k) * HW + pix];

        float yy = (float)(h + k / 3 - 1) + oy;
        float xx = (float)(w + k % 3 - 1) + ox;

        float y0f = floorf(yy), x0f = floorf(xx);
        float ty = yy - y0f, tx = xx - x0f;
        int y0 = (int)y0f, x0 = (int)x0f;

        float v00 = sampPC(fb, cf, y0,     x0);
        float v01 = sampPC(fb, cf, y0,     x0 + 1);
        float v10 = sampPC(fb, cf, y0 + 1, x0);
        float v11 = sampPC(fb, cf, y0 + 1, x0 + 1);

        float sk = (1.0f - ty) * (1.0f - tx) * v00
                 + (1.0f - ty) * tx          * v01
                 + ty          * (1.0f - tx) * v10
                 + ty          * tx          * v11;
        res = fmaf(av, sk, res);
    }
    fout[gid] = res;
    if (ffinal) ffinal[gid] = res;
}

extern "C" void kernel_launch(void* const* d_in, const int* in_sizes, int n_in,
                              void* d_out, int out_size, void* d_ws, size_t ws_size,
                              hipStream_t stream) {
    const float* feat_init  = (const float*)d_in[0];
    const float* guidance   = (const float*)d_in[1];
    const float* confidence = (const float*)d_in[2];
    const float* conv_w     = (const float*)d_in[3];
    const float* conv_b     = (const float*)d_in[4];
    const float* aff_scale  = (const float*)d_in[5];

    float* out        = (float*)d_out;
    float* feat_final = out;
    float* feats      = out + (size_t)NPIX;
    float* offset     = out + (size_t)19 * NPIX;
    float* affout     = out + (size_t)37 * NPIX;
    float* scale_out  = out + (size_t)46 * NPIX;

    int nblocks = (NPIX + 255) / 256;

    // workspace layout: tp (9*NPIX*12 B) | fcA | fcB
    size_t need = (size_t)9 * NPIX * 12 + (size_t)2 * NPIX * 4;

    if (ws_size >= need) {
        char* wsb = (char*)d_ws;
        Tap*   tpp = (Tap*)wsb;
        float* fcA = (float*)(wsb + (size_t)9 * NPIX * 12);
        float* fcB = fcA + NPIX;

        conv_fused<<<nblocks, 256, 0, stream>>>(guidance, conv_w, conv_b, aff_scale,
                                                feat_init, confidence,
                                                offset, affout, scale_out,
                                                tpp, fcA);

        float* fcIn = fcA;
        float* fcOut = fcB;
        for (int t = 0; t < 18; ++t) {
            float* cur = feats + (size_t)t * NPIX;
            prop2<<<nblocks, 256, 0, stream>>>(fcIn, confidence, tpp, cur,
                                               (t == 17) ? nullptr : fcOut,
                                               (t == 17) ? feat_final : nullptr);
            float* tmpp = fcIn; fcIn = fcOut; fcOut = tmpp;
        }
    } else {
        conv_fused<<<nblocks, 256, 0, stream>>>(guidance, conv_w, conv_b, aff_scale,
                                                feat_init, confidence,
                                                offset, affout, scale_out,
                                                nullptr, nullptr);
        const float* prev = feat_init;
        for (int t = 0; t < 18; ++t) {
            float* cur = feats + (size_t)t * NPIX;
            prop<<<nblocks, 256, 0, stream>>>(prev, confidence, offset, affout, cur,
                                              (t == 17) ? feat_final : nullptr);
            prev = cur;
        }
    }
}

// Round 6
// 714.663 us; speedup vs baseline: 1.3332x; 1.3332x over previous
//
#include <hip/hip_runtime.h>

#define BB 4
#define CG 8
#define HH 240
#define WW 1216
#define HW (HH*WW)
#define NPIX (BB*HW)

#define TW 128
#define TH 4
#define MG 8
#define LW (TW + 2*MG)          // 144
#define LH (TH + 2*MG)          // 20
#define NXT ((WW + TW - 1)/TW)  // 10
#define NYT (HH/TH)             // 60

struct __attribute__((packed, aligned(4))) Tap {
    unsigned pack;   // (y0+1) | (x0+1)<<8 | valid bits 19..22
    unsigned frac;   // ty q16 | tx q16 << 16
    float    av;     // exact affinity
};

// ---------------- fused conv + offsets/affinities + tap precompute ----------------
__global__ __launch_bounds__(256) void conv_fused(
    const float* __restrict__ g, const float* __restrict__ cw,
    const float* __restrict__ cb, const float* __restrict__ asc,
    const float* __restrict__ feat_init, const float* __restrict__ conf,
    float* __restrict__ out_off, float* __restrict__ out_aff,
    float* __restrict__ out_scale,
    Tap* __restrict__ tp, float* __restrict__ fc0)
{
    int gid = blockIdx.x * 256 + threadIdx.x;
    if (gid == 0) out_scale[0] = asc[0];
    if (gid >= NPIX) return;
    int w = gid % WW;
    int tmp = gid / WW;
    int h = tmp % HH;
    int b = tmp / HH;

    float acc[24];
    #pragma unroll
    for (int o = 0; o < 24; ++o) acc[o] = cb[o];

    const float* gb = g + (size_t)b * CG * HW;
    for (int i = 0; i < CG; ++i) {
        for (int kh = 0; kh < 3; ++kh) {
            int y = h + kh - 1;
            if ((unsigned)y >= (unsigned)HH) continue;
            for (int kw = 0; kw < 3; ++kw) {
                int x = w + kw - 1;
                if ((unsigned)x >= (unsigned)WW) continue;
                float xv = gb[i * HW + y * WW + x];
                #pragma unroll
                for (int o = 0; o < 24; ++o)
                    acc[o] = fmaf(xv, cw[((o * CG + i) * 3 + kh) * 3 + kw], acc[o]);
            }
        }
    }

    int pix = h * WW + w;

    float oyk[9], oxk[9];
    #pragma unroll
    for (int k = 0; k < 9; ++k) {
        if (k < 4)       { oyk[k] = acc[2 * k];     oxk[k] = acc[2 * k + 1]; }
        else if (k == 4) { oyk[k] = 0.0f;           oxk[k] = 0.0f; }
        else             { oyk[k] = acc[2 * k - 2]; oxk[k] = acc[2 * k - 1]; }
        out_off[(size_t)(b * 18 + 2 * k) * HW + pix]     = oyk[k];
        out_off[(size_t)(b * 18 + 2 * k + 1) * HW + pix] = oxk[k];
    }

    float inv = 1.0f / (asc[0] + 1e-8f);
    float a[8];
    float s = 0.0f;
    #pragma unroll
    for (int c = 0; c < 8; ++c) {
        a[c] = tanhf(acc[16 + c]) * inv;
        s += fabsf(a[c]);
    }
    s += 1e-4f;
    s = fmaxf(s, 1.0f);
    float sum = 0.0f;
    #pragma unroll
    for (int c = 0; c < 8; ++c) {
        a[c] = a[c] / s;
        sum += a[c];
    }
    float a9[9];
    #pragma unroll
    for (int c = 0; c < 4; ++c) a9[c] = a[c];
    a9[4] = 1.0f - sum;
    #pragma unroll
    for (int c = 4; c < 8; ++c) a9[c + 1] = a[c];

    #pragma unroll
    for (int k = 0; k < 9; ++k)
        out_aff[(size_t)(b * 9 + k) * HW + pix] = a9[k];

    if (tp) {
        #pragma unroll
        for (int k = 0; k < 9; ++k) {
            float yy = (float)(h + k / 3 - 1) + oyk[k];
            float xx = (float)(w + k % 3 - 1) + oxk[k];
            float y0f = floorf(yy), x0f = floorf(xx);
            float ty = yy - y0f, tx = xx - x0f;

            unsigned vy0 = (y0f >= 0.0f   && y0f <= 239.0f)  ? 1u : 0u;
            unsigned vy1 = (y0f >= -1.0f  && y0f <= 238.0f)  ? 1u : 0u;
            unsigned vx0 = (x0f >= 0.0f   && x0f <= 1215.0f) ? 1u : 0u;
            unsigned vx1 = (x0f >= -1.0f  && x0f <= 1214.0f) ? 1u : 0u;

            int y0i = (int)fminf(fmaxf(y0f, -1.0f), 239.0f);
            int x0i = (int)fminf(fmaxf(x0f, -1.0f), 1215.0f);

            unsigned pack = (unsigned)(y0i + 1) | ((unsigned)(x0i + 1) << 8)
                          | (vy0 << 19) | (vy1 << 20) | (vx0 << 21) | (vx1 << 22);
            unsigned tyq = (unsigned)(fminf(ty, 0.99999f) * 65535.0f + 0.5f);
            unsigned txq = (unsigned)(fminf(tx, 0.99999f) * 65535.0f + 0.5f);

            unsigned* t = (unsigned*)&tp[(size_t)k * NPIX + gid];
            t[0] = pack;
            t[1] = tyq | (txq << 16);
            t[2] = __float_as_uint(a9[k]);
        }
        fc0[gid] = feat_init[gid] * conf[gid];
    }
}

// ---------------- LDS-tiled propagation ----------------
__global__ __launch_bounds__(512) void prop3(
    const float* __restrict__ fcIn, const float* __restrict__ conf,
    const Tap* __restrict__ tp,
    float* __restrict__ fout, float* __restrict__ fcOut, float* __restrict__ ffinal)
{
    __shared__ float sfc[LH * LW];

    int bx = blockIdx.x % NXT;
    int by = blockIdx.x / NXT;
    int b  = blockIdx.y;
    int xs = bx * TW, ys = by * TH;

    int rlo = max(0, ys - MG), rhi = min(HH - 1, ys + TH - 1 + MG);
    int clo = max(0, xs - MG), chi = min(WW - 1, xs + TW - 1 + MG);
    int rh = rhi - rlo + 1;

    const float* fcb = fcIn + (size_t)b * HW;

    for (int i = threadIdx.x; i < rh * LW; i += 512) {
        int r = i / LW;
        int c = i - r * LW;
        int col = min(clo + c, WW - 1);
        sfc[i] = fcb[(rlo + r) * WW + col];
    }
    __syncthreads();

    int tx = threadIdx.x & (TW - 1);
    int tyy = threadIdx.x >> 7;
    int x = xs + tx, y = ys + tyy;
    if (x >= WW) return;
    int pix = y * WW + x;
    int gid = b * HW + pix;

    float res = 0.0f;
    #pragma unroll
    for (int k = 0; k < 9; ++k) {
        const unsigned* tw = (const unsigned*)&tp[(size_t)k * NPIX + gid];
        unsigned Px = tw[0];
        unsigned Py = tw[1];
        float    av = __uint_as_float(tw[2]);

        int y0 = (int)(Px & 0xffu) - 1;
        int x0 = (int)((Px >> 8) & 0x7ffu) - 1;
        float ty = (float)(Py & 0xffffu) * (1.0f / 65535.0f);
        float txf = (float)(Py >> 16)    * (1.0f / 65535.0f);
        float fy0 = (Px & (1u << 19)) ? 1.0f : 0.0f;
        float fy1 = (Px & (1u << 20)) ? 1.0f : 0.0f;
        float fx0 = (Px & (1u << 21)) ? 1.0f : 0.0f;
        float fx1 = (Px & (1u << 22)) ? 1.0f : 0.0f;

        int yA = max(y0, 0), yB = min(y0 + 1, HH - 1);
        int xA = max(x0, 0), xB = min(x0 + 1, WW - 1);

        float v00, v01, v10, v11;
        if (yA >= rlo && yB <= rhi && xA >= clo && xB <= chi) {
            int rA = (yA - rlo) * LW - clo;
            int rB = (yB - rlo) * LW - clo;
            v00 = sfc[rA + xA]; v01 = sfc[rA + xB];
            v10 = sfc[rB + xA]; v11 = sfc[rB + xB];
        } else {
            int rA = yA * WW, rB = yB * WW;
            v00 = fcb[rA + xA]; v01 = fcb[rA + xB];
            v10 = fcb[rB + xA]; v11 = fcb[rB + xB];
        }

        float cy0 = fy0 * (1.0f - ty),  cy1 = fy1 * ty;
        float cx0 = fx0 * (1.0f - txf), cx1 = fx1 * txf;

        float u0 = fmaf(cx1, v01, cx0 * v00);
        float u1 = fmaf(cx1, v11, cx0 * v10);
        res = fmaf(av, fmaf(cy1, u1, cy0 * u0), res);
    }
    fout[gid] = res;
    if (fcOut)  fcOut[gid]  = res * conf[gid];
    if (ffinal) ffinal[gid] = res;
}

// ---------------- fallback prop (no workspace needed) ----------------
__device__ __forceinline__ float sampPC(const float* __restrict__ fb,
                                        const float* __restrict__ cf,
                                        int y, int x) {
    bool valid = ((unsigned)y < (unsigned)HH) && ((unsigned)x < (unsigned)WW);
    int yc = min(max(y, 0), HH - 1);
    int xc = min(max(x, 0), WW - 1);
    int idx = yc * WW + xc;
    float v = fb[idx] * cf[idx];
    return valid ? v : 0.0f;
}

__global__ __launch_bounds__(256) void prop(
    const float* __restrict__ fp, const float* __restrict__ conf,
    const float* __restrict__ off, const float* __restrict__ aff,
    float* __restrict__ fout, float* __restrict__ ffinal)
{
    int gid = blockIdx.x * 256 + threadIdx.x;
    if (gid >= NPIX) return;
    int w = gid % WW;
    int tmp = gid / WW;
    int h = tmp % HH;
    int b = tmp / HH;
    int pix = h * WW + w;

    const float* fb = fp + (size_t)b * HW;
    const float* cf = conf + (size_t)b * HW;

    float res = 0.0f;
    #pragma unroll
    for (int k = 0; k < 9; ++k) {
        float oy = off[(size_t)(b * 18 + 2 * k) * HW + pix];
        float ox = off[(size_t)(b * 18 + 2 * k + 1) * HW + pix];
        float av = aff[(size_t)(b * 9 + k) * HW + pix];

        float yy = (float)(h + k / 3 - 1) + oy;
        float xx = (float)(w + k % 3 - 1) + ox;

        float y0f = floorf(yy), x0f = floorf(xx);
        float ty = yy - y0f, tx = xx - x0f;
        int y0 = (int)y0f, x0 = (int)x0f;

        float v00 = sampPC(fb, cf, y0,     x0);
        float v01 = sampPC(fb, cf, y0,     x0 + 1);
        float v10 = sampPC(fb, cf, y0 + 1, x0);
        float v11 = sampPC(fb, cf, y0 + 1, x0 + 1);

        float sk = (1.0f - ty) * (1.0f - tx) * v00
                 + (1.0f - ty) * tx          * v01
                 + ty          * (1.0f - tx) * v10
                 + ty          * tx          * v11;
        res = fmaf(av, sk, res);
    }
    fout[gid] = res;
    if (ffinal) ffinal[gid] = res;
}

extern "C" void kernel_launch(void* const* d_in, const int* in_sizes, int n_in,
                              void* d_out, int out_size, void* d_ws, size_t ws_size,
                              hipStream_t stream) {
    const float* feat_init  = (const float*)d_in[0];
    const float* guidance   = (const float*)d_in[1];
    const float* confidence = (const float*)d_in[2];
    const float* conv_w     = (const float*)d_in[3];
    const float* conv_b     = (const float*)d_in[4];
    const float* aff_scale  = (const float*)d_in[5];

    float* out        = (float*)d_out;
    float* feat_final = out;
    float* feats      = out + (size_t)NPIX;
    float* offset     = out + (size_t)19 * NPIX;
    float* affout     = out + (size_t)37 * NPIX;
    float* scale_out  = out + (size_t)46 * NPIX;

    int nblocks = (NPIX + 255) / 256;

    // workspace layout: tp (9*NPIX*12 B) | fcA | fcB
    size_t need = (size_t)9 * NPIX * 12 + (size_t)2 * NPIX * 4;

    if (ws_size >= need) {
        char* wsb = (char*)d_ws;
        Tap*   tpp = (Tap*)wsb;
        float* fcA = (float*)(wsb + (size_t)9 * NPIX * 12);
        float* fcB = fcA + NPIX;

        conv_fused<<<nblocks, 256, 0, stream>>>(guidance, conv_w, conv_b, aff_scale,
                                                feat_init, confidence,
                                                offset, affout, scale_out,
                                                tpp, fcA);

        dim3 pgrid(NXT * NYT, BB);
        float* fcIn = fcA;
        float* fcOut = fcB;
        for (int t = 0; t < 18; ++t) {
            float* cur = feats + (size_t)t * NPIX;
            prop3<<<pgrid, 512, 0, stream>>>(fcIn, confidence, tpp, cur,
                                             (t == 17) ? nullptr : fcOut,
                                             (t == 17) ? feat_final : nullptr);
            float* tmpp = fcIn; fcIn = fcOut; fcOut = tmpp;
        }
    } else {
        conv_fused<<<nblocks, 256, 0, stream>>>(guidance, conv_w, conv_b, aff_scale,
                                                feat_init, confidence,
                                                offset, affout, scale_out,
                                                nullptr, nullptr);
        const float* prev = feat_init;
        for (int t = 0; t < 18; ++t) {
            float* cur = feats + (size_t)t * NPIX;
            prop<<<nblocks, 256, 0, stream>>>(prev, confidence, offset, affout, cur,
                                              (t == 17) ? feat_final : nullptr);
            prev = cur;
        }
    }
}

// Round 7
// 630.710 us; speedup vs baseline: 1.5107x; 1.1331x over previous
//
#include <hip/hip_runtime.h>

#define BB 4
#define CG 8
#define HH 240
#define WW 1216
#define HW (HH*WW)
#define NPIX (BB*HW)

#define TW 128
#define TH 4
#define MG 8
#define LW (TW + 2*MG)          // 144
#define LH (TH + 2*MG)          // 20
#define NXT ((WW + TW - 1)/TW)  // 10
#define NYT (HH/TH)             // 60

// ---------------- fused conv + offsets/affinities + tap precompute ----------------
__global__ __launch_bounds__(256) void conv_fused(
    const float* __restrict__ g, const float* __restrict__ cw,
    const float* __restrict__ cb, const float* __restrict__ asc,
    const float* __restrict__ feat_init, const float* __restrict__ conf,
    float* __restrict__ out_off, float* __restrict__ out_aff,
    float* __restrict__ out_scale,
    unsigned long long* __restrict__ paf, float* __restrict__ tav,
    float* __restrict__ fc0)
{
    int gid = blockIdx.x * 256 + threadIdx.x;
    if (gid == 0) out_scale[0] = asc[0];
    if (gid >= NPIX) return;
    int w = gid % WW;
    int tmp = gid / WW;
    int h = tmp % HH;
    int b = tmp / HH;

    float acc[24];
    #pragma unroll
    for (int o = 0; o < 24; ++o) acc[o] = cb[o];

    const float* gb = g + (size_t)b * CG * HW;
    for (int i = 0; i < CG; ++i) {
        for (int kh = 0; kh < 3; ++kh) {
            int y = h + kh - 1;
            if ((unsigned)y >= (unsigned)HH) continue;
            for (int kw = 0; kw < 3; ++kw) {
                int x = w + kw - 1;
                if ((unsigned)x >= (unsigned)WW) continue;
                float xv = gb[i * HW + y * WW + x];
                #pragma unroll
                for (int o = 0; o < 24; ++o)
                    acc[o] = fmaf(xv, cw[((o * CG + i) * 3 + kh) * 3 + kw], acc[o]);
            }
        }
    }

    int pix = h * WW + w;

    float oyk[9], oxk[9];
    #pragma unroll
    for (int k = 0; k < 9; ++k) {
        if (k < 4)       { oyk[k] = acc[2 * k];     oxk[k] = acc[2 * k + 1]; }
        else if (k == 4) { oyk[k] = 0.0f;           oxk[k] = 0.0f; }
        else             { oyk[k] = acc[2 * k - 2]; oxk[k] = acc[2 * k - 1]; }
        __builtin_nontemporal_store(oyk[k], &out_off[(size_t)(b * 18 + 2 * k) * HW + pix]);
        __builtin_nontemporal_store(oxk[k], &out_off[(size_t)(b * 18 + 2 * k + 1) * HW + pix]);
    }

    float inv = 1.0f / (asc[0] + 1e-8f);
    float a[8];
    float s = 0.0f;
    #pragma unroll
    for (int c = 0; c < 8; ++c) {
        a[c] = tanhf(acc[16 + c]) * inv;
        s += fabsf(a[c]);
    }
    s += 1e-4f;
    s = fmaxf(s, 1.0f);
    float sum = 0.0f;
    #pragma unroll
    for (int c = 0; c < 8; ++c) {
        a[c] = a[c] / s;
        sum += a[c];
    }
    float a9[9];
    #pragma unroll
    for (int c = 0; c < 4; ++c) a9[c] = a[c];
    a9[4] = 1.0f - sum;
    #pragma unroll
    for (int c = 4; c < 8; ++c) a9[c + 1] = a[c];

    #pragma unroll
    for (int k = 0; k < 9; ++k)
        __builtin_nontemporal_store(a9[k], &out_aff[(size_t)(b * 9 + k) * HW + pix]);

    if (paf) {
        #pragma unroll
        for (int k = 0; k < 9; ++k) {
            tav[(size_t)k * NPIX + gid] = a9[k];
            if (k == 4) continue;
            int j = (k < 4) ? k : k - 1;

            float yy = (float)(h + k / 3 - 1) + oyk[k];
            float xx = (float)(w + k % 3 - 1) + oxk[k];
            float y0f = floorf(yy), x0f = floorf(xx);
            float ty = yy - y0f, tx = xx - x0f;

            unsigned vy0 = (y0f >= 0.0f   && y0f <= 239.0f)  ? 1u : 0u;
            unsigned vy1 = (y0f >= -1.0f  && y0f <= 238.0f)  ? 1u : 0u;
            unsigned vx0 = (x0f >= 0.0f   && x0f <= 1215.0f) ? 1u : 0u;
            unsigned vx1 = (x0f >= -1.0f  && x0f <= 1214.0f) ? 1u : 0u;

            int y0i = (int)fminf(fmaxf(y0f, -1.0f), 239.0f);
            int x0i = (int)fminf(fmaxf(x0f, -1.0f), 1215.0f);

            unsigned pack = (unsigned)(y0i + 1) | ((unsigned)(x0i + 1) << 8)
                          | (vy0 << 19) | (vy1 << 20) | (vx0 << 21) | (vx1 << 22);
            unsigned tyq = (unsigned)(fminf(ty, 0.99999f) * 65535.0f + 0.5f);
            unsigned txq = (unsigned)(fminf(tx, 0.99999f) * 65535.0f + 0.5f);
            unsigned frac = tyq | (txq << 16);

            paf[(size_t)j * NPIX + gid] =
                (unsigned long long)pack | ((unsigned long long)frac << 32);
        }
        fc0[gid] = feat_init[gid] * conf[gid];
    }
}

// ---------------- LDS-tiled propagation, SoA taps ----------------
__global__ __launch_bounds__(512) void prop4(
    const float* __restrict__ fcIn, const float* __restrict__ conf,
    const unsigned long long* __restrict__ paf, const float* __restrict__ tav,
    float* __restrict__ fout, float* __restrict__ fcOut, float* __restrict__ ffinal)
{
    __shared__ float sfc[LH * LW];

    int bx = blockIdx.x % NXT;
    int by = blockIdx.x / NXT;
    int b  = blockIdx.y;
    int xs = bx * TW, ys = by * TH;

    int rlo = max(0, ys - MG), rhi = min(HH - 1, ys + TH - 1 + MG);
    int clo = max(0, xs - MG), chi = min(WW - 1, xs + TW - 1 + MG);
    int rh = rhi - rlo + 1;

    const float* fcb = fcIn + (size_t)b * HW;

    for (int i = threadIdx.x; i < rh * LW; i += 512) {
        int r = i / LW;
        int c = i - r * LW;
        int col = min(clo + c, WW - 1);
        sfc[i] = fcb[(rlo + r) * WW + col];
    }
    __syncthreads();

    int tx = threadIdx.x & (TW - 1);
    int tyy = threadIdx.x >> 7;
    int x = xs + tx, y = ys + tyy;
    if (x >= WW) return;
    int pix = y * WW + x;
    int gid = b * HW + pix;

    // center tap: exact sample at (y,x)
    float res = tav[(size_t)4 * NPIX + gid] *
                sfc[(y - rlo) * LW + (x - clo)];

    #pragma unroll
    for (int j = 0; j < 8; ++j) {
        int k = (j < 4) ? j : j + 1;
        unsigned long long pf = paf[(size_t)j * NPIX + gid];
        float av = tav[(size_t)k * NPIX + gid];

        unsigned Px = (unsigned)pf;
        unsigned Py = (unsigned)(pf >> 32);

        int y0 = (int)(Px & 0xffu) - 1;
        int x0 = (int)((Px >> 8) & 0x7ffu) - 1;
        float ty = (float)(Py & 0xffffu) * (1.0f / 65535.0f);
        float txf = (float)(Py >> 16)    * (1.0f / 65535.0f);
        float fy0 = (Px & (1u << 19)) ? 1.0f : 0.0f;
        float fy1 = (Px & (1u << 20)) ? 1.0f : 0.0f;
        float fx0 = (Px & (1u << 21)) ? 1.0f : 0.0f;
        float fx1 = (Px & (1u << 22)) ? 1.0f : 0.0f;

        int yA = max(y0, 0), yB = min(y0 + 1, HH - 1);
        int xA = max(x0, 0), xB = min(x0 + 1, WW - 1);

        float v00, v01, v10, v11;
        if (yA >= rlo && yB <= rhi && xA >= clo && xB <= chi) {
            int rA = (yA - rlo) * LW - clo;
            int rB = (yB - rlo) * LW - clo;
            v00 = sfc[rA + xA]; v01 = sfc[rA + xB];
            v10 = sfc[rB + xA]; v11 = sfc[rB + xB];
        } else {
            int rA = yA * WW, rB = yB * WW;
            v00 = fcb[rA + xA]; v01 = fcb[rA + xB];
            v10 = fcb[rB + xA]; v11 = fcb[rB + xB];
        }

        float cy0 = fy0 * (1.0f - ty),  cy1 = fy1 * ty;
        float cx0 = fx0 * (1.0f - txf), cx1 = fx1 * txf;

        float u0 = fmaf(cx1, v01, cx0 * v00);
        float u1 = fmaf(cx1, v11, cx0 * v10);
        res = fmaf(av, fmaf(cy1, u1, cy0 * u0), res);
    }
    __builtin_nontemporal_store(res, &fout[gid]);
    if (fcOut)  fcOut[gid] = res * conf[gid];
    if (ffinal) __builtin_nontemporal_store(res, &ffinal[gid]);
}

// ---------------- fallback prop (no workspace needed) ----------------
__device__ __forceinline__ float sampPC(const float* __restrict__ fb,
                                        const float* __restrict__ cf,
                                        int y, int x) {
    bool valid = ((unsigned)y < (unsigned)HH) && ((unsigned)x < (unsigned)WW);
    int yc = min(max(y, 0), HH - 1);
    int xc = min(max(x, 0), WW - 1);
    int idx = yc * WW + xc;
    float v = fb[idx] * cf[idx];
    return valid ? v : 0.0f;
}

__global__ __launch_bounds__(256) void prop(
    const float* __restrict__ fp, const float* __restrict__ conf,
    const float* __restrict__ off, const float* __restrict__ aff,
    float* __restrict__ fout, float* __restrict__ ffinal)
{
    int gid = blockIdx.x * 256 + threadIdx.x;
    if (gid >= NPIX) return;
    int w = gid % WW;
    int tmp = gid / WW;
    int h = tmp % HH;
    int b = tmp / HH;
    int pix = h * WW + w;

    const float* fb = fp + (size_t)b * HW;
    const float* cf = conf + (size_t)b * HW;

    float res = 0.0f;
    #pragma unroll
    for (int k = 0; k < 9; ++k) {
        float oy = off[(size_t)(b * 18 + 2 * k) * HW + pix];
        float ox = off[(size_t)(b * 18 + 2 * k + 1) * HW + pix];
        float av = aff[(size_t)(b * 9 + k) * HW + pix];

        float yy = (float)(h + k / 3 - 1) + oy;
        float xx = (float)(w + k % 3 - 1) + ox;

        float y0f = floorf(yy), x0f = floorf(xx);
        float ty = yy - y0f, tx = xx - x0f;
        int y0 = (int)y0f, x0 = (int)x0f;

        float v00 = sampPC(fb, cf, y0,     x0);
        float v01 = sampPC(fb, cf, y0,     x0 + 1);
        float v10 = sampPC(fb, cf, y0 + 1, x0);
        float v11 = sampPC(fb, cf, y0 + 1, x0 + 1);

        float sk = (1.0f - ty) * (1.0f - tx) * v00
                 + (1.0f - ty) * tx          * v01
                 + ty          * (1.0f - tx) * v10
                 + ty          * tx          * v11;
        res = fmaf(av, sk, res);
    }
    fout[gid] = res;
    if (ffinal) ffinal[gid] = res;
}

extern "C" void kernel_launch(void* const* d_in, const int* in_sizes, int n_in,
                              void* d_out, int out_size, void* d_ws, size_t ws_size,
                              hipStream_t stream) {
    const float* feat_init  = (const float*)d_in[0];
    const float* guidance   = (const float*)d_in[1];
    const float* confidence = (const float*)d_in[2];
    const float* conv_w     = (const float*)d_in[3];
    const float* conv_b     = (const float*)d_in[4];
    const float* aff_scale  = (const float*)d_in[5];

    float* out        = (float*)d_out;
    float* feat_final = out;
    float* feats      = out + (size_t)NPIX;
    float* offset     = out + (size_t)19 * NPIX;
    float* affout     = out + (size_t)37 * NPIX;
    float* scale_out  = out + (size_t)46 * NPIX;

    int nblocks = (NPIX + 255) / 256;

    // workspace layout: paf (8*NPIX u64) | tav (9*NPIX f32) | fcA | fcB
    size_t need = (size_t)8 * NPIX * 8 + (size_t)9 * NPIX * 4 + (size_t)2 * NPIX * 4;

    if (ws_size >= need) {
        char* wsb = (char*)d_ws;
        unsigned long long* paf = (unsigned long long*)wsb;
        float* tav = (float*)(wsb + (size_t)8 * NPIX * 8);
        float* fcA = (float*)(wsb + (size_t)8 * NPIX * 8 + (size_t)9 * NPIX * 4);
        float* fcB = fcA + NPIX;

        conv_fused<<<nblocks, 256, 0, stream>>>(guidance, conv_w, conv_b, aff_scale,
                                                feat_init, confidence,
                                                offset, affout, scale_out,
                                                paf, tav, fcA);

        dim3 pgrid(NXT * NYT, BB);
        float* fcIn = fcA;
        float* fcOut = fcB;
        for (int t = 0; t < 18; ++t) {
            float* cur = feats + (size_t)t * NPIX;
            prop4<<<pgrid, 512, 0, stream>>>(fcIn, confidence, paf, tav, cur,
                                             (t == 17) ? nullptr : fcOut,
                                             (t == 17) ? feat_final : nullptr);
            float* tmpp = fcIn; fcIn = fcOut; fcOut = tmpp;
        }
    } else {
        conv_fused<<<nblocks, 256, 0, stream>>>(guidance, conv_w, conv_b, aff_scale,
                                                feat_init, confidence,
                                                offset, affout, scale_out,
                                                nullptr, nullptr, nullptr);
        const float* prev = feat_init;
        for (int t = 0; t < 18; ++t) {
            float* cur = feats + (size_t)t * NPIX;
            prop<<<nblocks, 256, 0, stream>>>(prev, confidence, offset, affout, cur,
                                              (t == 17) ? feat_final : nullptr);
            prev = cur;
        }
    }
}